// Round 1
// baseline (1060.762 us; speedup 1.0000x reference)
//
#include <hip/hip_runtime.h>

#define NN 100000
#define NE 1600000
#define D 64

// ---------------------------------------------------------------------------
// Scatter: one 64-lane wave per edge. lane t does msg[dst][t] += x[src][t].
// withDeg: lane 0 also counts degree (layer 1 only).
// ---------------------------------------------------------------------------
__global__ __launch_bounds__(256) void scatter_kernel(
    const float* __restrict__ x,
    const int* __restrict__ src,
    const int* __restrict__ dst,
    float* __restrict__ msg,
    float* __restrict__ deg,
    int E, int withDeg)
{
    int tid = blockIdx.x * blockDim.x + threadIdx.x;  // < 102.4M, fits int
    int e = tid >> 6;
    if (e >= E) return;
    int lane = threadIdx.x & 63;
    int s = src[e];   // all 64 lanes same addr -> broadcast from cache
    int d = dst[e];
    float v = x[s * D + lane];                 // coalesced 256B per wave
    unsafeAtomicAdd(&msg[d * D + lane], v);    // global_atomic_add_f32
    if (withDeg && lane == 0) unsafeAtomicAdd(&deg[d], 1.0f);
}

// deg -> 1/max(deg,1), in place
__global__ __launch_bounds__(256) void rdeg_kernel(float* deg, int n)
{
    int i = blockIdx.x * blockDim.x + threadIdx.x;
    if (i < n) deg[i] = 1.0f / fmaxf(deg[i], 1.0f);
}

// ---------------------------------------------------------------------------
// Dense: out[n][o] = sum_k x[n][k]*Wself[o][k] + (msg[n][k]*rdeg[n])*Wneigh[o][k]
//        (+ bias, optional relu).  16 nodes per 256-thread block.
// Thread t: node j = t/16, outputs ob..ob+3 with ob = (t%16)*4.
// W staged transposed [k][o] in LDS -> float4 reads conflict-free over o.
// x/msg rows staged with stride 68 (pad 4) -> 4 node-groups hit distinct banks.
// ---------------------------------------------------------------------------
template <int RELU>
__global__ __launch_bounds__(256) void dense_kernel(
    const float* __restrict__ x,
    const float* __restrict__ msg,
    const float* __restrict__ rdeg,
    const float* __restrict__ Wself,
    const float* __restrict__ Wneigh,
    const float* __restrict__ bias,
    float* __restrict__ out)
{
    __shared__ __align__(16) float WTs[64 * 64];
    __shared__ __align__(16) float WTn[64 * 64];
    __shared__ __align__(16) float xs[16 * 68];
    __shared__ __align__(16) float ms[16 * 68];

    const int tid = threadIdx.x;
    const int n0 = blockIdx.x * 16;

    // Stage W transposed: LDS[k*64+o] = W[o*64+k]. LDS writes contiguous
    // (conflict-free); global reads are strided but the 16KB matrix is
    // L1/L2-resident after the first blocks.
    #pragma unroll
    for (int r = 0; r < 16; ++r) {
        int idx = r * 256 + tid;
        int o = idx & 63, k = idx >> 6;
        WTs[idx] = Wself[o * 64 + k];
        WTn[idx] = Wneigh[o * 64 + k];
    }

    // Stage x and msg*rdeg rows (coalesced float4 global loads)
    {
        int idx = tid * 4;
        int js = idx >> 6, ks = idx & 63;
        float4 gx = *(const float4*)(x + (size_t)n0 * D + idx);
        float4 gm = *(const float4*)(msg + (size_t)n0 * D + idx);
        float rd = rdeg[n0 + js];
        gm.x *= rd; gm.y *= rd; gm.z *= rd; gm.w *= rd;
        *(float4*)&xs[js * 68 + ks] = gx;
        *(float4*)&ms[js * 68 + ks] = gm;
    }
    __syncthreads();

    const int j = tid >> 4;
    const int ob = (tid & 15) * 4;

    float acc0 = 0.f, acc1 = 0.f, acc2 = 0.f, acc3 = 0.f;
    #pragma unroll
    for (int k = 0; k < 64; k += 4) {
        float4 xv = *(const float4*)&xs[j * 68 + k];
        float4 mv = *(const float4*)&ms[j * 68 + k];
        const float* xk = &xv.x;
        const float* mk = &mv.x;
        #pragma unroll
        for (int kk = 0; kk < 4; ++kk) {
            float4 wsv = *(const float4*)&WTs[(k + kk) * 64 + ob];
            float4 wnv = *(const float4*)&WTn[(k + kk) * 64 + ob];
            float xv1 = xk[kk], mv1 = mk[kk];
            acc0 += xv1 * wsv.x + mv1 * wnv.x;
            acc1 += xv1 * wsv.y + mv1 * wnv.y;
            acc2 += xv1 * wsv.z + mv1 * wnv.z;
            acc3 += xv1 * wsv.w + mv1 * wnv.w;
        }
    }

    float4 b4 = *(const float4*)(bias + ob);
    float4 r;
    r.x = acc0 + b4.x; r.y = acc1 + b4.y;
    r.z = acc2 + b4.z; r.w = acc3 + b4.w;
    if (RELU) {
        r.x = fmaxf(r.x, 0.f); r.y = fmaxf(r.y, 0.f);
        r.z = fmaxf(r.z, 0.f); r.w = fmaxf(r.w, 0.f);
    }
    // address = n0*64 + j*64 + ob = n0*64 + tid*4 -> fully coalesced
    *(float4*)(out + (size_t)n0 * D + tid * 4) = r;
}

extern "C" void kernel_launch(void* const* d_in, const int* in_sizes, int n_in,
                              void* d_out, int out_size, void* d_ws, size_t ws_size,
                              hipStream_t stream)
{
    const float* in_feat = (const float*)d_in[0];
    const int*   src     = (const int*)d_in[1];
    const int*   dst     = (const int*)d_in[2];
    const float* Ws1     = (const float*)d_in[3];
    const float* Wn1     = (const float*)d_in[4];
    const float* b1      = (const float*)d_in[5];
    const float* Ws2     = (const float*)d_in[6];
    const float* Wn2     = (const float*)d_in[7];
    const float* b2      = (const float*)d_in[8];
    float* out = (float*)d_out;

    float* ws  = (float*)d_ws;
    float* deg = ws;                  // 100352 floats (deg, then rdeg in place)
    float* msg = ws + 100352;         // 6.4M floats
    float* h1  = msg + 6400000;       // 6.4M floats

    // zero deg + msg in one shot (contiguous)
    hipMemsetAsync(deg, 0, (size_t)(100352 + 6400000) * sizeof(float), stream);

    const int scatter_threads = NE * 64;               // 102.4M
    const int scatter_blocks = (scatter_threads + 255) / 256;

    // Layer 1
    scatter_kernel<<<scatter_blocks, 256, 0, stream>>>(in_feat, src, dst, msg, deg, NE, 1);
    rdeg_kernel<<<(NN + 255) / 256, 256, 0, stream>>>(deg, NN);
    dense_kernel<1><<<NN / 16, 256, 0, stream>>>(in_feat, msg, deg, Ws1, Wn1, b1, h1);

    // Layer 2
    hipMemsetAsync(msg, 0, (size_t)6400000 * sizeof(float), stream);
    scatter_kernel<<<scatter_blocks, 256, 0, stream>>>(h1, src, dst, msg, deg, NE, 0);
    dense_kernel<0><<<NN / 16, 256, 0, stream>>>(h1, msg, deg, Ws2, Wn2, b2, out);
}

// Round 2
// 551.373 us; speedup vs baseline: 1.9239x; 1.9239x over previous
//
#include <hip/hip_runtime.h>

#define NN 100000
#define NE 1600000
#define D 64
#define NPAD 100352           // NN padded to 392*256
#define NBLK 392              // scan blocks

// ---------------------------------------------------------------------------
// CSR build: histogram -> 3-kernel exclusive scan -> fill
// ---------------------------------------------------------------------------
__global__ __launch_bounds__(256) void hist_kernel(const int* __restrict__ dst,
                                                   int* __restrict__ deg)
{
    int e = blockIdx.x * 256 + threadIdx.x;   // grid exact: 6250*256 == NE
    atomicAdd(&deg[dst[e]], 1);
}

__global__ __launch_bounds__(256) void scan1_kernel(const int* __restrict__ deg,
                                                    int* __restrict__ rowptr,
                                                    int* __restrict__ bsum)
{
    __shared__ int s[256];
    int i = blockIdx.x * 256 + threadIdx.x;
    int v = deg[i];
    s[threadIdx.x] = v;
    __syncthreads();
    #pragma unroll
    for (int off = 1; off < 256; off <<= 1) {
        int t = (threadIdx.x >= off) ? s[threadIdx.x - off] : 0;
        __syncthreads();
        s[threadIdx.x] += t;
        __syncthreads();
    }
    rowptr[i] = s[threadIdx.x] - v;           // exclusive, block-local
    if (threadIdx.x == 255) bsum[blockIdx.x] = s[255];
}

__global__ __launch_bounds__(512) void scan2_kernel(const int* __restrict__ bsum,
                                                    int* __restrict__ boff)
{
    __shared__ int s[512];
    int t = threadIdx.x;
    int v = (t < NBLK) ? bsum[t] : 0;
    s[t] = v;
    __syncthreads();
    #pragma unroll
    for (int off = 1; off < 512; off <<= 1) {
        int u = (t >= off) ? s[t - off] : 0;
        __syncthreads();
        s[t] += u;
        __syncthreads();
    }
    if (t < NBLK) boff[t] = s[t] - v;         // exclusive block offsets
}

__global__ __launch_bounds__(256) void scan3_kernel(int* __restrict__ rowptr,
                                                    const int* __restrict__ boff,
                                                    int* __restrict__ cursor)
{
    int i = blockIdx.x * 256 + threadIdx.x;
    int r = rowptr[i] + boff[blockIdx.x];
    rowptr[i] = r;
    cursor[i] = r;
}

__global__ __launch_bounds__(256) void fill_kernel(const int* __restrict__ src,
                                                   const int* __restrict__ dst,
                                                   int* __restrict__ cursor,
                                                   int* __restrict__ col)
{
    int e = blockIdx.x * 256 + threadIdx.x;   // grid exact
    int d = dst[e];
    int p = atomicAdd(&cursor[d], 1);
    col[p] = src[e];
}

// ---------------------------------------------------------------------------
// Gather-aggregate: one wave per node. lane = feature dim. Mean over neighbors.
// ---------------------------------------------------------------------------
__global__ __launch_bounds__(256) void aggregate_kernel(
    const float* __restrict__ x,
    const int* __restrict__ rowptr,
    const int* __restrict__ col,
    float* __restrict__ hn)
{
    int n = blockIdx.x * 4 + (threadIdx.x >> 6);   // grid exact: 25000*4 == NN
    int lane = threadIdx.x & 63;
    int beg = rowptr[n], end = rowptr[n + 1];
    float acc0 = 0.f, acc1 = 0.f;
    for (int j = beg; j < end; j += 64) {
        int cnt = min(end - j, 64);
        int ci = (lane < cnt) ? col[j + lane] : 0;  // coalesced index prefetch
        int t = 0;
        for (; t + 1 < cnt; t += 2) {
            int s0 = __shfl(ci, t, 64);
            int s1 = __shfl(ci, t + 1, 64);
            acc0 += x[(s0 << 6) + lane];            // 256B coalesced row gather
            acc1 += x[(s1 << 6) + lane];
        }
        if (t < cnt) {
            int s0 = __shfl(ci, t, 64);
            acc0 += x[(s0 << 6) + lane];
        }
    }
    float deg = (float)(end - beg);
    hn[(n << 6) + lane] = (acc0 + acc1) / fmaxf(deg, 1.0f);
}

// ---------------------------------------------------------------------------
// Dense: out[n][o] = sum_k x[n][k]*Ws[o][k] + hn[n][k]*Wn[o][k] (+b, opt relu)
// 64 nodes/block, 256 threads: thread = (og = tid&15 -> outputs og*4..+3,
//                                        ng = tid>>4 -> nodes ng*4..+3)
// LDS: W transposed [k][o] (stride 64, conflict-free b128 over o).
//      x/hn transposed [k][node] stride 64 with per-k rotation swizzle
//      c = (node + ((k>>2)&7)*8) & 63  -> b128 reads conflict-free,
//      staging writes only 4-way. Total LDS = 64 KB exactly.
// ---------------------------------------------------------------------------
__device__ inline void fma4(float4& a, float s, const float4& w)
{
    a.x += s * w.x; a.y += s * w.y; a.z += s * w.z; a.w += s * w.w;
}

template <int RELU>
__global__ __launch_bounds__(256) void dense_kernel(
    const float* __restrict__ x,
    const float* __restrict__ hn,
    const float* __restrict__ Ws,
    const float* __restrict__ Wn,
    const float* __restrict__ bias,
    float* __restrict__ out)
{
    __shared__ __align__(16) float WTs[4096];
    __shared__ __align__(16) float WTn[4096];
    __shared__ __align__(16) float xT[4096];
    __shared__ __align__(16) float mT[4096];

    const int tid = threadIdx.x;
    const int n0 = blockIdx.x * 64;

    // Stage W transposed: WTs[k*64+o] = Ws[o*64+k] (16KB matrix, L2-resident)
    #pragma unroll
    for (int r = 0; r < 16; ++r) {
        int idx = r * 256 + tid;          // idx = k*64 + o
        int o = idx & 63, k = idx >> 6;
        WTs[idx] = Ws[o * 64 + k];
        WTn[idx] = Wn[o * 64 + k];
    }

    // Stage x / hn transposed with rotation swizzle (coalesced 1KB/wave global)
    #pragma unroll
    for (int r = 0; r < 4; ++r) {
        int s4 = r * 256 + tid;           // float4 slot 0..1023
        int node = s4 >> 4;               // 0..63
        int k4 = (s4 & 15) << 2;          // 0..60
        int gn = n0 + node;
        float4 vx = make_float4(0.f, 0.f, 0.f, 0.f), vm = vx;
        if (gn < NN) {
            vx = *(const float4*)(x  + gn * 64 + k4);
            vm = *(const float4*)(hn + gn * 64 + k4);
        }
        int c = (node + (s4 & 7) * 8) & 63;   // rot = ((k4>>2)&7)*8
        xT[(k4 + 0) * 64 + c] = vx.x;
        xT[(k4 + 1) * 64 + c] = vx.y;
        xT[(k4 + 2) * 64 + c] = vx.z;
        xT[(k4 + 3) * 64 + c] = vx.w;
        mT[(k4 + 0) * 64 + c] = vm.x;
        mT[(k4 + 1) * 64 + c] = vm.y;
        mT[(k4 + 2) * 64 + c] = vm.z;
        mT[(k4 + 3) * 64 + c] = vm.w;
    }
    __syncthreads();

    const int og = tid & 15;
    const int ng = tid >> 4;
    const int ob = og * 4;
    const int nb = ng * 4;

    float4 a0 = make_float4(0.f, 0.f, 0.f, 0.f), a1 = a0, a2 = a0, a3 = a0;

    #pragma unroll 4
    for (int k4 = 0; k4 < 64; k4 += 4) {
        int cx = (nb + ((k4 >> 2) & 7) * 8) & 63;
        #pragma unroll
        for (int i = 0; i < 4; ++i) {
            int k = k4 + i;
            float4 ws = *(const float4*)&WTs[k * 64 + ob];
            float4 wn = *(const float4*)&WTn[k * 64 + ob];
            float4 xv = *(const float4*)&xT[k * 64 + cx];
            float4 mv = *(const float4*)&mT[k * 64 + cx];
            fma4(a0, xv.x, ws); fma4(a0, mv.x, wn);
            fma4(a1, xv.y, ws); fma4(a1, mv.y, wn);
            fma4(a2, xv.z, ws); fma4(a2, mv.z, wn);
            fma4(a3, xv.w, ws); fma4(a3, mv.w, wn);
        }
    }

    float4 b4 = *(const float4*)(bias + ob);
    float4 accs[4] = { a0, a1, a2, a3 };
    #pragma unroll
    for (int nn = 0; nn < 4; ++nn) {
        int gn = n0 + nb + nn;
        if (gn < NN) {
            float4 r;
            r.x = accs[nn].x + b4.x;
            r.y = accs[nn].y + b4.y;
            r.z = accs[nn].z + b4.z;
            r.w = accs[nn].w + b4.w;
            if (RELU) {
                r.x = fmaxf(r.x, 0.f); r.y = fmaxf(r.y, 0.f);
                r.z = fmaxf(r.z, 0.f); r.w = fmaxf(r.w, 0.f);
            }
            *(float4*)(out + gn * 64 + ob) = r;
        }
    }
}

extern "C" void kernel_launch(void* const* d_in, const int* in_sizes, int n_in,
                              void* d_out, int out_size, void* d_ws, size_t ws_size,
                              hipStream_t stream)
{
    const float* in_feat = (const float*)d_in[0];
    const int*   src     = (const int*)d_in[1];
    const int*   dst     = (const int*)d_in[2];
    const float* Ws1     = (const float*)d_in[3];
    const float* Wn1     = (const float*)d_in[4];
    const float* b1      = (const float*)d_in[5];
    const float* Ws2     = (const float*)d_in[6];
    const float* Wn2     = (const float*)d_in[7];
    const float* b2      = (const float*)d_in[8];
    float* out = (float*)d_out;

    // Workspace layout (ints are 4B): 33.2 MB total
    int* ideg   = (int*)d_ws;            // NPAD
    int* rowptr = ideg + NPAD;           // NPAD+256 alloc (uses [0..NN])
    int* cursor = rowptr + NPAD + 256;   // NPAD
    int* bsum   = cursor + NPAD;         // 512
    int* boff   = bsum + 512;            // 512
    int* col    = boff + 512;            // NE
    float* h1   = (float*)(col + NE);    // NN*64 floats
    float* hn   = out;                   // reuse d_out as h_neigh scratch (safe:
                                         // dense reads its own block's rows before writing them)

    hipMemsetAsync(ideg, 0, (size_t)NPAD * sizeof(int), stream);

    // CSR build (shared by both layers)
    hist_kernel <<<NE / 256, 256, 0, stream>>>(dst, ideg);
    scan1_kernel<<<NBLK, 256, 0, stream>>>(ideg, rowptr, bsum);
    scan2_kernel<<<1, 512, 0, stream>>>(bsum, boff);
    scan3_kernel<<<NBLK, 256, 0, stream>>>(rowptr, boff, cursor);
    fill_kernel <<<NE / 256, 256, 0, stream>>>(src, dst, cursor, col);

    const int dense_blocks = (NN + 63) / 64;   // 1563

    // Layer 1
    aggregate_kernel<<<NN / 4, 256, 0, stream>>>(in_feat, rowptr, col, hn);
    dense_kernel<1><<<dense_blocks, 256, 0, stream>>>(in_feat, hn, Ws1, Wn1, b1, h1);

    // Layer 2
    aggregate_kernel<<<NN / 4, 256, 0, stream>>>(h1, rowptr, col, hn);
    dense_kernel<0><<<dense_blocks, 256, 0, stream>>>(h1, hn, Ws2, Wn2, b2, out);
}